// Round 15
// baseline (481.168 us; speedup 1.0000x reference)
//
#include <hip/hip_runtime.h>
#include <math.h>

typedef unsigned short u16;
typedef __attribute__((ext_vector_type(8))) short bf16x8;   // 8 bf16 = 4 VGPRs
typedef __attribute__((ext_vector_type(4))) float f32x4;

static constexpr int kN = 10000;
static constexpr int kNpad = 10240;       // 40 * 256 rows per relation range
static constexpr int kD = 1024;
static constexpr int kR = 8;
static constexpr int kE = 80000;
static constexpr int kKz = 2 * kD;        // 2048 : [u | x]
static constexpr int kCrows = kNpad * (kR + 1);  // 92160 compact y_c rows (worst case)

#define GLB(p) ((const __attribute__((address_space(1))) unsigned int*)(const void*)(p))
#define LDSP(p) ((__attribute__((address_space(3))) unsigned int*)(p))

__device__ __forceinline__ u16 f2bf(float f) {
    union { float f; unsigned int i; } c; c.f = f;
    unsigned int u = c.i;
    return (u16)((u + 0x7FFFu + ((u >> 16) & 1u)) >> 16);   // RNE
}
__device__ __forceinline__ float bf2f(u16 u) {
    union { unsigned int i; float f; } c; c.i = ((unsigned int)u) << 16;
    return c.f;
}
__device__ __forceinline__ ushort4 f2bf4(float4 v) {
    ushort4 o; o.x = f2bf(v.x); o.y = f2bf(v.y); o.z = f2bf(v.z); o.w = f2bf(v.w);
    return o;
}

__global__ void zero16(uint4* __restrict__ p, long n16) {
    long i = (long)blockIdx.x * blockDim.x + threadIdx.x;
    long st = (long)gridDim.x * blockDim.x;
    uint4 z = make_uint4(0, 0, 0, 0);
    for (; i < n16; i += st) p[i] = z;
}

// Per edge: histogram dst (for CSR) and flag (rel, src) presence.
__global__ void mark_edges(const int* __restrict__ src, const int* __restrict__ dst,
                           const int* __restrict__ etype,
                           int* __restrict__ cntd, int* __restrict__ flag) {
    int e = blockIdx.x * blockDim.x + threadIdx.x;
    if (e < kE) {
        atomicAdd(&cntd[dst[e]], 1);
        flag[etype[e] * kN + src[e]] = 1;   // idempotent plain store
    }
}

// FUSED: block 0 = exclusive scan of cnt -> rowptr + zero cursor;
// blocks 1..9 = per-relation compact scans (block 9 = root identity).
__global__ __launch_bounds__(1024) void scan_combo(const int* __restrict__ cnt,
                                                   int* __restrict__ rowptr,
                                                   int* __restrict__ cursor,
                                                   const int* __restrict__ flag,
                                                   int* __restrict__ row_src,
                                                   int* __restrict__ pos_tab,
                                                   int* __restrict__ relcnt9) {
    __shared__ int wsum[16];
    __shared__ int carry;
    const int tid = threadIdx.x;
    const int lane = tid & 63;
    const int w = tid >> 6;

    if (blockIdx.x == 0) {
        if (tid == 0) carry = 0;
        const int nchunk = (kN + 1024) / 1024;
        for (int ch = 0; ch < nchunk; ++ch) {
            int idx = ch * 1024 + tid;
            int v = (idx < kN) ? cnt[idx] : 0;
            int s = v;
#pragma unroll
            for (int off = 1; off < 64; off <<= 1) {
                int t = __shfl_up(s, off, 64);
                if (lane >= off) s += t;
            }
            if (lane == 63) wsum[w] = s;
            __syncthreads();
            if (w == 0 && lane < 16) {
                int t = wsum[lane];
#pragma unroll
                for (int off = 1; off < 16; off <<= 1) {
                    int tt = __shfl_up(t, off, 64);
                    if (lane >= off) t += tt;
                }
                wsum[lane] = t;
            }
            __syncthreads();
            int wpre = (w > 0) ? wsum[w - 1] : 0;
            int incl = s + wpre + carry;
            int excl = incl - v;
            if (idx <= kN) rowptr[idx] = excl;
            if (idx < kN) cursor[idx] = 0;
            __syncthreads();
            if (tid == 1023) carry = incl;
            __syncthreads();
        }
        return;
    }

    const int rr = blockIdx.x - 1;      // 0..8
    if (rr == kR) {   // root range: identity
        for (int i = tid; i < kNpad; i += 1024) row_src[i] = i;
        if (tid == 0) relcnt9[0] = kN;
        return;
    }
    const int r = rr;
    const int base = kNpad * (r + 1);
    if (tid == 0) carry = 0;
    const int nchunk = (kN + 1023) / 1024;
    for (int ch = 0; ch < nchunk; ++ch) {
        int idx = ch * 1024 + tid;
        int v = (idx < kN) ? flag[r * kN + idx] : 0;
        int s = v;
#pragma unroll
        for (int off = 1; off < 64; off <<= 1) {
            int t = __shfl_up(s, off, 64);
            if (lane >= off) s += t;
        }
        if (lane == 63) wsum[w] = s;
        __syncthreads();
        if (w == 0 && lane < 16) {
            int t = wsum[lane];
#pragma unroll
            for (int off = 1; off < 16; off <<= 1) {
                int tt = __shfl_up(t, off, 64);
                if (lane >= off) t += tt;
            }
            wsum[lane] = t;
        }
        __syncthreads();
        int wpre = (w > 0) ? wsum[w - 1] : 0;
        int incl = s + wpre + carry;
        int excl = incl - v;
        if (idx < kN && v) {
            row_src[base + excl] = idx;
            pos_tab[r * kN + idx] = base + excl;
        }
        __syncthreads();
        if (tid == 1023) carry = incl;
        __syncthreads();
    }
    if (tid == 0) relcnt9[r + 1] = carry;
}

// erec = (y_c row << 3) | rel, CSR-grouped by dst.
__global__ void fill_edges(const int* __restrict__ src, const int* __restrict__ dst,
                           const int* __restrict__ etype, const int* __restrict__ rowptr,
                           int* __restrict__ cursor, const int* __restrict__ pos_tab,
                           int* __restrict__ erec) {
    int e = blockIdx.x * blockDim.x + threadIdx.x;
    if (e < kE) {
        int d = dst[e], r = etype[e], s = src[e];
        int pos = rowptr[d] + atomicAdd(&cursor[d], 1);
        erec[pos] = (pos_tab[r * kN + s] << 3) | r;
    }
}

// FUSED: x fp32 -> bf16 into ga[:,1024:2048]; zero both halves of pad rows.
__global__ void prep_ga(const float* __restrict__ x, u16* __restrict__ ga) {
    int row = blockIdx.x;
    int c = threadIdx.x << 2;
    if (row < kN) {
        float4 v = *reinterpret_cast<const float4*>(x + (size_t)row * kD + c);
        *reinterpret_cast<ushort4*>(ga + (size_t)row * kKz + kD + c) = f2bf4(v);
    } else {
        ushort4 z4;
        z4.x = 0; z4.y = 0; z4.z = 0; z4.w = 0;
        *reinterpret_cast<ushort4*>(ga + (size_t)row * kKz + c) = z4;
        *reinterpret_cast<ushort4*>(ga + (size_t)row * kKz + kD + c) = z4;
    }
}

// FUSED: all transposes in one launch, z-batched 1024x1024 squares.
__global__ void transpose_all(const float* __restrict__ root,
                              const float* __restrict__ weight,
                              const float* __restrict__ wgate,
                              u16* __restrict__ Bt9, u16* __restrict__ wg_t) {
    const int z = blockIdx.z;
    const float* S;
    u16* D;
    int ldD;
    if (z == 0)       { S = root;                              D = Bt9;                       ldD = kD; }
    else if (z <= 8)  { S = weight + (size_t)(z - 1) * kD * kD; D = Bt9 + (size_t)z * kD * kD; ldD = kD; }
    else              { S = wgate + (size_t)(z - 9) * kD * kD;  D = wg_t + (size_t)(z - 9) * kD; ldD = kKz; }
    __shared__ float t[32][33];
    int c0 = blockIdx.x * 32, r0 = blockIdx.y * 32;
    int x = threadIdx.x, y = threadIdx.y;   // block (32,8)
#pragma unroll
    for (int i = 0; i < 32; i += 8)
        t[y + i][x] = S[(size_t)(r0 + y + i) * kD + c0 + x];
    __syncthreads();
#pragma unroll
    for (int i = 0; i < 32; i += 8)
        D[(size_t)(c0 + y + i) * ldD + r0 + x] = f2bf(t[x][y + i]);
}

// One block (256 thr) per dst row; parallel per-relation count; x4 MLP loop.
__global__ __launch_bounds__(256) void aggregate(const u16* __restrict__ yc,
                                                 const float* __restrict__ bias,
                                                 const int* __restrict__ rowptr,
                                                 const int* __restrict__ erec,
                                                 u16* __restrict__ ga) {
    const int d = blockIdx.x;
    const int c = threadIdx.x << 2;
    const int e0 = rowptr[d], e1 = rowptr[d + 1];

    __shared__ int cc8[kR];
    __shared__ float rs[kR];
    if (threadIdx.x < kR) cc8[threadIdx.x] = 0;
    __syncthreads();
    if (threadIdx.x < 64) {
        for (int e = e0 + threadIdx.x; e < e1; e += 64)
            atomicAdd(&cc8[erec[e] & 7], 1);
    }
    __syncthreads();
    if (threadIdx.x < kR)
        rs[threadIdx.x] = 1.0f / fmaxf((float)cc8[threadIdx.x], 1.0f);
    __syncthreads();

    ushort4 rv = *reinterpret_cast<const ushort4*>(yc + (size_t)d * kD + c);
    float4 bv = *reinterpret_cast<const float4*>(bias + c);
    float4 acc = make_float4(bf2f(rv.x) + bv.x, bf2f(rv.y) + bv.y,
                             bf2f(rv.z) + bv.z, bf2f(rv.w) + bv.w);

    int e = e0;
    for (; e + 3 < e1; e += 4) {
        int rec0 = erec[e], rec1 = erec[e + 1], rec2 = erec[e + 2], rec3 = erec[e + 3];
        ushort4 v0 = *reinterpret_cast<const ushort4*>(yc + (size_t)(rec0 >> 3) * kD + c);
        ushort4 v1 = *reinterpret_cast<const ushort4*>(yc + (size_t)(rec1 >> 3) * kD + c);
        ushort4 v2 = *reinterpret_cast<const ushort4*>(yc + (size_t)(rec2 >> 3) * kD + c);
        ushort4 v3 = *reinterpret_cast<const ushort4*>(yc + (size_t)(rec3 >> 3) * kD + c);
        float s0 = rs[rec0 & 7], s1 = rs[rec1 & 7], s2 = rs[rec2 & 7], s3 = rs[rec3 & 7];
        acc.x += s0 * bf2f(v0.x); acc.y += s0 * bf2f(v0.y);
        acc.z += s0 * bf2f(v0.z); acc.w += s0 * bf2f(v0.w);
        acc.x += s1 * bf2f(v1.x); acc.y += s1 * bf2f(v1.y);
        acc.z += s1 * bf2f(v1.z); acc.w += s1 * bf2f(v1.w);
        acc.x += s2 * bf2f(v2.x); acc.y += s2 * bf2f(v2.y);
        acc.z += s2 * bf2f(v2.z); acc.w += s2 * bf2f(v2.w);
        acc.x += s3 * bf2f(v3.x); acc.y += s3 * bf2f(v3.y);
        acc.z += s3 * bf2f(v3.z); acc.w += s3 * bf2f(v3.w);
    }
    for (; e < e1; ++e) {
        int rec = erec[e];
        float sc = rs[rec & 7];
        ushort4 v = *reinterpret_cast<const ushort4*>(yc + (size_t)(rec >> 3) * kD + c);
        acc.x += sc * bf2f(v.x); acc.y += sc * bf2f(v.y);
        acc.z += sc * bf2f(v.z); acc.w += sc * bf2f(v.w);
    }
    *reinterpret_cast<ushort4*>(ga + (size_t)d * kKz + c) = f2bf4(acc);
}

// GEMM1 (compacted): y_c[grow] = x_bf[row_src[grow]] @ W_{rel(grow)}^T.
// FROZEN at r12 (best: 181.5 us, 699 TF, MfmaUtil 29.7). Deep-pipeline
// 4-phase, 256x256/BK=64/8-wave/dbuf, whole-tile vmcnt(6) guard at ph0,
// pre-barrier ds_read hoisting, fences flanking barriers, T2 swizzle, T5
// setprio. Seven schedule variants measured; residual gap to m248's 848 TF
// is barrier convoy + 1-block/CU LDS occupancy floor -- not schedule.
__global__ __launch_bounds__(512, 2) void gemm_compact(
    const u16* __restrict__ xb, int ldx,
    const u16* __restrict__ Bt9,
    const int* __restrict__ row_src, const int* __restrict__ relcnt9,
    u16* __restrict__ yc)
{
    const int t0 = blockIdx.y;
    const int relidx = t0 / 40;
    const int lt = t0 - relidx * 40;
    if (lt * 256 >= relcnt9[relidx]) return;   // uniform early-exit (before barriers)

    __shared__ u16 sA[2][256 * 64];   // 64KB
    __shared__ u16 sB[2][256 * 64];   // 64KB

    const int tid = threadIdx.x;
    const int wave = tid >> 6;
    const int lane = tid & 63;

    const int row0 = t0 * 256;
    const int col0 = blockIdx.x * 256;

    const int s_row = tid >> 3;                                   // 0..63
    const int s_src = ((tid & 7) ^ (s_row & 7)) * 8;              // swizzled source col
    const int wbase = wave * 512;                                 // LDS u16 base per wave

    const u16* gA[4];
    const u16* gB[4];
#pragma unroll
    for (int q = 0; q < 4; ++q) {
        gA[q] = xb + (size_t)row_src[row0 + q * 64 + s_row] * ldx + s_src;
        gB[q] = Bt9 + (size_t)(relidx * kD + col0 + q * 64 + s_row) * kD + s_src;
    }

    auto stageA = [&](int b, int h) {
        u16* dA = &sA[b][0];
#pragma unroll
        for (int q = 2 * h; q < 2 * h + 2; ++q) {
            __builtin_amdgcn_global_load_lds(GLB(gA[q]), LDSP(dA + q * 4096 + wbase), 16, 0, 0);
            gA[q] += 64;
        }
    };
    auto stageB = [&](int b, int h) {
        u16* dB = &sB[b][0];
#pragma unroll
        for (int q = 2 * h; q < 2 * h + 2; ++q) {
            __builtin_amdgcn_global_load_lds(GLB(gB[q]), LDSP(dB + q * 4096 + wbase), 16, 0, 0);
            gB[q] += 64;
        }
    };

    const int wm = (wave >> 2) * 128;      // 0 / 128
    const int wn = (wave & 3) * 64;        // 0..192
    const int fm = lane & 15;
    const int g4 = lane >> 4;              // 0..3
    const int pc0 = ((g4) ^ (fm & 7)) * 8;        // ks=0 physical chunk (u16 off)
    const int pc1 = ((4 | g4) ^ (fm & 7)) * 8;    // ks=1

    f32x4 zf = {0.0f, 0.0f, 0.0f, 0.0f};
    f32x4 acc[8][4];
#pragma unroll
    for (int i = 0; i < 8; ++i)
#pragma unroll
        for (int j = 0; j < 4; ++j) acc[i][j] = zf;

    constexpr int T = kD / 64;   // 16 K-tiles
    // prologue stage order: A0(0) A1(0) B0(0) B1(0) -> buf0; B0(1) B1(1) -> buf1
    stageA(0, 0); stageA(0, 1); stageB(0, 0); stageB(0, 1);
    stageB(1, 0); stageB(1, 1);

    bf16x8 af[8], bfl[4], bfh[4];

    for (int t = 0; t < T; ++t) {
        const int cb = t & 1, nb = cb ^ 1;
        const bool pf1 = (t + 1 < T);
        const bool pf2 = (t + 2 < T);
        const u16* cA = sA[cb];
        const u16* cB = sB[cb];

        // ========= ph0: stage A0(t+1); whole-tile guard; reads; MFMA Q00
        if (pf1) stageA(nb, 0);
        if (t < T - 1) asm volatile("s_waitcnt vmcnt(6)" ::: "memory");
        else           asm volatile("s_waitcnt vmcnt(0)" ::: "memory");
        __builtin_amdgcn_s_barrier();
        asm volatile("" ::: "memory");
#pragma unroll
        for (int i = 0; i < 4; ++i) {
            af[2 * i]     = *reinterpret_cast<const bf16x8*>(&cA[(wm + i * 16 + fm) * 64 + pc0]);
            af[2 * i + 1] = *reinterpret_cast<const bf16x8*>(&cA[(wm + i * 16 + fm) * 64 + pc1]);
        }
#pragma unroll
        for (int j = 0; j < 2; ++j) {
            bfl[2 * j]     = *reinterpret_cast<const bf16x8*>(&cB[(wn + j * 16 + fm) * 64 + pc0]);
            bfl[2 * j + 1] = *reinterpret_cast<const bf16x8*>(&cB[(wn + j * 16 + fm) * 64 + pc1]);
        }
        __builtin_amdgcn_s_setprio(1);
#pragma unroll
        for (int i = 0; i < 4; ++i)
#pragma unroll
            for (int j = 0; j < 2; ++j) {
                acc[i][j] = __builtin_amdgcn_mfma_f32_16x16x32_bf16(bfl[2 * j], af[2 * i], acc[i][j], 0, 0, 0);
                acc[i][j] = __builtin_amdgcn_mfma_f32_16x16x32_bf16(bfl[2 * j + 1], af[2 * i + 1], acc[i][j], 0, 0, 0);
            }
        __builtin_amdgcn_s_setprio(0);

        // ========= ph1: reads B1-range (pre-barrier); stage A1(t+1); MFMA Q01
#pragma unroll
        for (int j = 0; j < 2; ++j) {
            bfh[2 * j]     = *reinterpret_cast<const bf16x8*>(&cB[(wn + 32 + j * 16 + fm) * 64 + pc0]);
            bfh[2 * j + 1] = *reinterpret_cast<const bf16x8*>(&cB[(wn + 32 + j * 16 + fm) * 64 + pc1]);
        }
        if (pf1) stageA(nb, 1);
        asm volatile("" ::: "memory");
        __builtin_amdgcn_s_barrier();
        asm volatile("" ::: "memory");
        __builtin_amdgcn_s_setprio(1);
#pragma unroll
        for (int i = 0; i < 4; ++i)
#pragma unroll
            for (int j = 0; j < 2; ++j) {
                acc[i][2 + j] = __builtin_amdgcn_mfma_f32_16x16x32_bf16(bfh[2 * j], af[2 * i], acc[i][2 + j], 0, 0, 0);
                acc[i][2 + j] = __builtin_amdgcn_mfma_f32_16x16x32_bf16(bfh[2 * j + 1], af[2 * i + 1], acc[i][2 + j], 0, 0, 0);
            }
        __builtin_amdgcn_s_setprio(0);

        // ========= ph2: reads A hi-rows (pre-barrier); MFMA Q11
#pragma unroll
        for (int i = 0; i < 4; ++i) {
            af[2 * i]     = *reinterpret_cast<const bf16x8*>(&cA[(wm + 64 + i * 16 + fm) * 64 + pc0]);
            af[2 * i + 1] = *reinterpret_cast<const bf16x8*>(&cA[(wm + 64 + i * 16 + fm) * 64 + pc1]);
        }
        asm volatile("" ::: "memory");
        __builtin_amdgcn_s_barrier();
        asm volatile("" ::: "memory");
        __builtin_amdgcn_s_setprio(1);
#pragma unroll
        for (int i = 0; i < 4; ++i)
#pragma unroll
            for (int j = 0; j < 2; ++j) {
                acc[4 + i][2 + j] = __builtin_amdgcn_mfma_f32_16x16x32_bf16(bfh[2 * j], af[2 * i], acc[4 + i][2 + j], 0, 0, 0);
                acc[4 + i][2 + j] = __builtin_amdgcn_mfma_f32_16x16x32_bf16(bfh[2 * j + 1], af[2 * i + 1], acc[4 + i][2 + j], 0, 0, 0);
            }
        __builtin_amdgcn_s_setprio(0);

        // ========= ph3: stage B0(t+2)+B1(t+2); MFMA Q10 (register reuse)
        if (pf2) { stageB(cb, 0); stageB(cb, 1); }
        asm volatile("" ::: "memory");
        __builtin_amdgcn_s_barrier();
        asm volatile("" ::: "memory");
        __builtin_amdgcn_s_setprio(1);
#pragma unroll
        for (int i = 0; i < 4; ++i)
#pragma unroll
            for (int j = 0; j < 2; ++j) {
                acc[4 + i][j] = __builtin_amdgcn_mfma_f32_16x16x32_bf16(bfl[2 * j], af[2 * i], acc[4 + i][j], 0, 0, 0);
                acc[4 + i][j] = __builtin_amdgcn_mfma_f32_16x16x32_bf16(bfl[2 * j + 1], af[2 * i + 1], acc[4 + i][j], 0, 0, 0);
            }
        __builtin_amdgcn_s_setprio(0);
    }

    // Transposed C/D: row = wm + i*16 + fm, col = wn + j*16 + g4*4 + reg
    const int cq = g4 * 4;
#pragma unroll
    for (int i = 0; i < 8; ++i) {
        int row = row0 + wm + i * 16 + fm;   // y_c fully padded: no guard
#pragma unroll
        for (int j = 0; j < 4; ++j) {
            int col = col0 + wn + j * 16 + cq;
            f32x4 v = acc[i][j];
            ushort4 o;
            o.x = f2bf(v[0]); o.y = f2bf(v[1]); o.z = f2bf(v[2]); o.w = f2bf(v[3]);
            *reinterpret_cast<ushort4*>(yc + (size_t)row * kD + col) = o;
        }
    }
}

// GEMM2 (r15): ported to the r12 deep-pipeline schedule. 128x128 tile,
// BK=64, 4 waves (wave 64x64), 2-buf 64KB LDS -> 2 blocks/CU. Same phase
// structure and safety proof as gemm_compact (identical dependence graph):
// ph0 stage A0(t+1) + whole-tile vmcnt(6) guard; ph1 pre-barrier bfh reads +
// stage A1(t+1); ph2 pre-barrier af-hi reads; ph3 stage B0,B1(t+2). Fences
// flank all barriers. 256 threads: 32 rows per gload_lds inst (tid>>3),
// same XOR chunk swizzle (all offsets ==0 mod 8 so pc formulas carry over).
// z = A @ Bt^T + bias; h = tanh(u)*z + x*(1-z) -> Cf (fused combine).
// XCD-chunked bijective block swizzle retained.
__global__ __launch_bounds__(256, 2) void gemm_mfma_gate(
    const u16* __restrict__ A, int lda,
    const u16* __restrict__ Bt, int ldb, int K,
    int M, const float* __restrict__ bias,
    float* __restrict__ Cf, const u16* __restrict__ uga, const float* __restrict__ xo)
{
    __shared__ u16 sA[2][128 * 64];   // 32KB
    __shared__ u16 sB[2][128 * 64];   // 32KB

    const int tid = threadIdx.x;
    const int wave = tid >> 6;
    const int lane = tid & 63;

    constexpr int GX = kD / 128;      // 8 col tiles
    constexpr int GY = kNpad / 128;   // 80 row tiles
    const int lin = blockIdx.y * GX + blockIdx.x;
    const int xcd = lin & 7;          // default XCD of this block
    const int pos = lin >> 3;         // 0..79 within this XCD
    const int ty = xcd * (GY / 8) + (pos >> 3);
    const int tx = pos & 7;

    const int row0 = ty * 128;
    const int col0 = tx * 128;

    const int s_row = tid >> 3;                                   // 0..31
    const int s_src = ((tid & 7) ^ (s_row & 7)) * 8;              // swizzled source col
    const int wbase = wave * 512;                                 // LDS u16 base per wave

    const u16* gA[4];
    const u16* gB[4];
#pragma unroll
    for (int q = 0; q < 4; ++q) {
        gA[q] = A + (size_t)(row0 + q * 32 + s_row) * lda + s_src;
        gB[q] = Bt + (size_t)(col0 + q * 32 + s_row) * ldb + s_src;
    }

    auto stageA = [&](int b, int h) {
        u16* dA = &sA[b][0];
#pragma unroll
        for (int q = 2 * h; q < 2 * h + 2; ++q) {
            __builtin_amdgcn_global_load_lds(GLB(gA[q]), LDSP(dA + q * 2048 + wbase), 16, 0, 0);
            gA[q] += 64;
        }
    };
    auto stageB = [&](int b, int h) {
        u16* dB = &sB[b][0];
#pragma unroll
        for (int q = 2 * h; q < 2 * h + 2; ++q) {
            __builtin_amdgcn_global_load_lds(GLB(gB[q]), LDSP(dB + q * 2048 + wbase), 16, 0, 0);
            gB[q] += 64;
        }
    };

    const int wm = (wave >> 1) * 64;       // 0 / 64
    const int wn = (wave & 1) * 64;        // 0 / 64
    const int fm = lane & 15;
    const int g4 = lane >> 4;              // 0..3
    const int pc0 = ((g4) ^ (fm & 7)) * 8;        // ks=0 physical chunk (u16 off)
    const int pc1 = ((4 | g4) ^ (fm & 7)) * 8;    // ks=1

    f32x4 zf = {0.0f, 0.0f, 0.0f, 0.0f};
    f32x4 acc[4][4];
#pragma unroll
    for (int i = 0; i < 4; ++i)
#pragma unroll
        for (int j = 0; j < 4; ++j) acc[i][j] = zf;

    const int T = K >> 6;   // 32 K-tiles
    // prologue: A0(0) A1(0) B0(0) B1(0) -> buf0; B0(1) B1(1) -> buf1
    stageA(0, 0); stageA(0, 1); stageB(0, 0); stageB(0, 1);
    stageB(1, 0); stageB(1, 1);

    bf16x8 af[4], bfl[4], bfh[4];

    for (int t = 0; t < T; ++t) {
        const int cb = t & 1, nb = cb ^ 1;
        const bool pf1 = (t + 1 < T);
        const bool pf2 = (t + 2 < T);
        const u16* cA = sA[cb];
        const u16* cB = sB[cb];

        // ========= ph0: stage A0(t+1); whole-tile guard; reads; MFMA Q00
        if (pf1) stageA(nb, 0);
        if (t < T - 1) asm volatile("s_waitcnt vmcnt(6)" ::: "memory");
        else           asm volatile("s_waitcnt vmcnt(0)" ::: "memory");
        __builtin_amdgcn_s_barrier();
        asm volatile("" ::: "memory");
#pragma unroll
        for (int i = 0; i < 2; ++i) {
            af[2 * i]     = *reinterpret_cast<const bf16x8*>(&cA[(wm + i * 16 + fm) * 64 + pc0]);
            af[2 * i + 1] = *reinterpret_cast<const bf16x8*>(&cA[(wm + i * 16 + fm) * 64 + pc1]);
        }
#pragma unroll
        for (int j = 0; j < 2; ++j) {
            bfl[2 * j]     = *reinterpret_cast<const bf16x8*>(&cB[(wn + j * 16 + fm) * 64 + pc0]);
            bfl[2 * j + 1] = *reinterpret_cast<const bf16x8*>(&cB[(wn + j * 16 + fm) * 64 + pc1]);
        }
        __builtin_amdgcn_s_setprio(1);
#pragma unroll
        for (int i = 0; i < 2; ++i)
#pragma unroll
            for (int j = 0; j < 2; ++j) {
                acc[i][j] = __builtin_amdgcn_mfma_f32_16x16x32_bf16(bfl[2 * j], af[2 * i], acc[i][j], 0, 0, 0);
                acc[i][j] = __builtin_amdgcn_mfma_f32_16x16x32_bf16(bfl[2 * j + 1], af[2 * i + 1], acc[i][j], 0, 0, 0);
            }
        __builtin_amdgcn_s_setprio(0);

        // ========= ph1: reads B1-range (pre-barrier); stage A1(t+1); MFMA Q01
#pragma unroll
        for (int j = 0; j < 2; ++j) {
            bfh[2 * j]     = *reinterpret_cast<const bf16x8*>(&cB[(wn + 32 + j * 16 + fm) * 64 + pc0]);
            bfh[2 * j + 1] = *reinterpret_cast<const bf16x8*>(&cB[(wn + 32 + j * 16 + fm) * 64 + pc1]);
        }
        if (pf1) stageA(nb, 1);
        asm volatile("" ::: "memory");
        __builtin_amdgcn_s_barrier();
        asm volatile("" ::: "memory");
        __builtin_amdgcn_s_setprio(1);
#pragma unroll
        for (int i = 0; i < 2; ++i)
#pragma unroll
            for (int j = 0; j < 2; ++j) {
                acc[i][2 + j] = __builtin_amdgcn_mfma_f32_16x16x32_bf16(bfh[2 * j], af[2 * i], acc[i][2 + j], 0, 0, 0);
                acc[i][2 + j] = __builtin_amdgcn_mfma_f32_16x16x32_bf16(bfh[2 * j + 1], af[2 * i + 1], acc[i][2 + j], 0, 0, 0);
            }
        __builtin_amdgcn_s_setprio(0);

        // ========= ph2: reads A hi-rows (pre-barrier); MFMA Q11
#pragma unroll
        for (int i = 0; i < 2; ++i) {
            af[2 * i]     = *reinterpret_cast<const bf16x8*>(&cA[(wm + 32 + i * 16 + fm) * 64 + pc0]);
            af[2 * i + 1] = *reinterpret_cast<const bf16x8*>(&cA[(wm + 32 + i * 16 + fm) * 64 + pc1]);
        }
        asm volatile("" ::: "memory");
        __builtin_amdgcn_s_barrier();
        asm volatile("" ::: "memory");
        __builtin_amdgcn_s_setprio(1);
#pragma unroll
        for (int i = 0; i < 2; ++i)
#pragma unroll
            for (int j = 0; j < 2; ++j) {
                acc[2 + i][2 + j] = __builtin_amdgcn_mfma_f32_16x16x32_bf16(bfh[2 * j], af[2 * i], acc[2 + i][2 + j], 0, 0, 0);
                acc[2 + i][2 + j] = __builtin_amdgcn_mfma_f32_16x16x32_bf16(bfh[2 * j + 1], af[2 * i + 1], acc[2 + i][2 + j], 0, 0, 0);
            }
        __builtin_amdgcn_s_setprio(0);

        // ========= ph3: stage B0(t+2)+B1(t+2); MFMA Q10 (register reuse)
        if (pf2) { stageB(cb, 0); stageB(cb, 1); }
        asm volatile("" ::: "memory");
        __builtin_amdgcn_s_barrier();
        asm volatile("" ::: "memory");
        __builtin_amdgcn_s_setprio(1);
#pragma unroll
        for (int i = 0; i < 2; ++i)
#pragma unroll
            for (int j = 0; j < 2; ++j) {
                acc[2 + i][j] = __builtin_amdgcn_mfma_f32_16x16x32_bf16(bfl[2 * j], af[2 * i], acc[2 + i][j], 0, 0, 0);
                acc[2 + i][j] = __builtin_amdgcn_mfma_f32_16x16x32_bf16(bfl[2 * j + 1], af[2 * i + 1], acc[2 + i][j], 0, 0, 0);
            }
        __builtin_amdgcn_s_setprio(0);
    }

    const int cq = g4 * 4;
#pragma unroll
    for (int i = 0; i < 4; ++i) {
        int row = row0 + wm + i * 16 + fm;
        if (row >= M) continue;
#pragma unroll
        for (int j = 0; j < 4; ++j) {
            int col = col0 + wn + j * 16 + cq;
            f32x4 v = acc[i][j];
            float4 bv = *reinterpret_cast<const float4*>(bias + col);
            v[0] += bv.x; v[1] += bv.y; v[2] += bv.z; v[3] += bv.w;
            ushort4 ur = *reinterpret_cast<const ushort4*>(uga + (size_t)row * kKz + col);
            float4 xr = *reinterpret_cast<const float4*>(xo + (size_t)row * kD + col);
            float4 h;
            h.x = tanhf(bf2f(ur.x)) * v[0] + xr.x * (1.0f - v[0]);
            h.y = tanhf(bf2f(ur.y)) * v[1] + xr.y * (1.0f - v[1]);
            h.z = tanhf(bf2f(ur.z)) * v[2] + xr.z * (1.0f - v[2]);
            h.w = tanhf(bf2f(ur.w)) * v[3] + xr.w * (1.0f - v[3]);
            *reinterpret_cast<float4*>(Cf + (size_t)row * kD + col) = h;
        }
    }
}

extern "C" void kernel_launch(void* const* d_in, const int* in_sizes, int n_in,
                              void* d_out, int out_size, void* d_ws, size_t ws_size,
                              hipStream_t stream) {
    (void)in_sizes; (void)n_in; (void)out_size; (void)ws_size;

    const float* x     = (const float*)d_in[0];
    const int* eidx    = (const int*)d_in[1];
    const int* etype   = (const int*)d_in[2];
    const float* weight= (const float*)d_in[3];
    const float* root  = (const float*)d_in[4];
    const float* bias  = (const float*)d_in[5];
    const float* wgate = (const float*)d_in[6];
    const float* bgate = (const float*)d_in[7];
    float* out = (float*)d_out;

    const int* src = eidx;
    const int* dst = eidx + kE;

    // ---- workspace ----
    char* ws = (char*)d_ws;
    size_t off = 0;
    u16* yc   = (u16*)(ws + off);    off += (size_t)kCrows * kD * 2;   // 188.7 MB
    u16* ga   = (u16*)(ws + off);    off += (size_t)kNpad * kKz * 2;   //  41.9 MB
    u16* Bt9  = (u16*)(ws + off);    off += (size_t)(kR + 1) * kD * kD * 2; // 18.9 MB
    u16* wg_t = (u16*)(ws + off);    off += (size_t)kD * kKz * 2;      //   4.2 MB
    int* cntd    = (int*)(ws + off); off += (size_t)kN * 4;            // 10000
    int* flag    = (int*)(ws + off); off += (size_t)kR * kN * 4;       // 80000
    int* row_src = (int*)(ws + off); off += (size_t)kCrows * 4;        // 92160
    int* pos_tab = (int*)(ws + off); off += (size_t)kR * kN * 4;
    int* rowp    = (int*)(ws + off); off += (size_t)(kN + 16) * 4;
    int* curs    = (int*)(ws + off); off += (size_t)kN * 4;
    int* erec    = (int*)(ws + off); off += (size_t)kE * 4;
    int* relcnt9 = (int*)(ws + off); off += 16 * 4;

    // zero cntd+flag+row_src in one pass (contiguous, 182160 ints)
    zero16<<<180, 256, 0, stream>>>((uint4*)cntd, (long)(kN + kR * kN + kCrows) / 4);

    mark_edges<<<(kE + 255) / 256, 256, 0, stream>>>(src, dst, etype, cntd, flag);

    // fused: block 0 = rowptr scan, blocks 1..9 = per-relation compaction
    scan_combo<<<kR + 2, 1024, 0, stream>>>(cntd, rowp, curs, flag, row_src,
                                            pos_tab, relcnt9);

    fill_edges<<<(kE + 255) / 256, 256, 0, stream>>>(src, dst, etype, rowp, curs,
                                                     pos_tab, erec);

    // fused: x -> bf16 into ga[:,1024:2048] + zero pad rows [kN,kNpad)
    prep_ga<<<kNpad, 256, 0, stream>>>(x, ga);

    // fused: root/weight -> Bt9, wgate -> wg_t, one launch (z=0..10)
    {
        dim3 b(32, 8);
        transpose_all<<<dim3(kD / 32, kD / 32, 11), b, 0, stream>>>(root, weight,
                                                                    wgate, Bt9, wg_t);
    }

    // GEMM1 (compacted): y_c = gathered x rows @ per-relation W
    dim3 g1(kD / 256, kCrows / 256);   // 4 x 360, ~2/3 exit early
    gemm_compact<<<g1, 512, 0, stream>>>(ga + kD, kKz, Bt9, row_src, relcnt9, yc);

    // aggregate: u -> ga[:,0:1024] (bf16)
    aggregate<<<kN, 256, 0, stream>>>(yc, bias, rowp, erec, ga);

    // GEMM2: z = ga @ wg_t + b_gate; h = tanh(u)*z + x*(1-z) -> out
    dim3 g2(kD / 128, kNpad / 128);    // 8 x 80
    gemm_mfma_gate<<<g2, 256, 0, stream>>>(ga, kKz, wg_t, kKz, kKz, kN, bgate, out, ga, x);
}

// Round 16
// 441.152 us; speedup vs baseline: 1.0907x; 1.0907x over previous
//
#include <hip/hip_runtime.h>
#include <math.h>

typedef unsigned short u16;
typedef __attribute__((ext_vector_type(8))) short bf16x8;   // 8 bf16 = 4 VGPRs
typedef __attribute__((ext_vector_type(4))) float f32x4;

static constexpr int kN = 10000;
static constexpr int kNpad = 10240;       // 40 * 256 rows per relation range
static constexpr int kD = 1024;
static constexpr int kR = 8;
static constexpr int kE = 80000;
static constexpr int kKz = 2 * kD;        // 2048 : [u | x]
static constexpr int kCrows = kNpad * (kR + 1);  // 92160 compact y_c rows (worst case)

#define GLB(p) ((const __attribute__((address_space(1))) unsigned int*)(const void*)(p))
#define LDSP(p) ((__attribute__((address_space(3))) unsigned int*)(p))

__device__ __forceinline__ u16 f2bf(float f) {
    union { float f; unsigned int i; } c; c.f = f;
    unsigned int u = c.i;
    return (u16)((u + 0x7FFFu + ((u >> 16) & 1u)) >> 16);   // RNE
}
__device__ __forceinline__ float bf2f(u16 u) {
    union { unsigned int i; float f; } c; c.i = ((unsigned int)u) << 16;
    return c.f;
}
__device__ __forceinline__ ushort4 f2bf4(float4 v) {
    ushort4 o; o.x = f2bf(v.x); o.y = f2bf(v.y); o.z = f2bf(v.z); o.w = f2bf(v.w);
    return o;
}

__global__ void zero16(uint4* __restrict__ p, long n16) {
    long i = (long)blockIdx.x * blockDim.x + threadIdx.x;
    long st = (long)gridDim.x * blockDim.x;
    uint4 z = make_uint4(0, 0, 0, 0);
    for (; i < n16; i += st) p[i] = z;
}

// Per edge: histogram dst (for CSR) and flag (rel, src) presence.
__global__ void mark_edges(const int* __restrict__ src, const int* __restrict__ dst,
                           const int* __restrict__ etype,
                           int* __restrict__ cntd, int* __restrict__ flag) {
    int e = blockIdx.x * blockDim.x + threadIdx.x;
    if (e < kE) {
        atomicAdd(&cntd[dst[e]], 1);
        flag[etype[e] * kN + src[e]] = 1;   // idempotent plain store
    }
}

// FUSED: block 0 = exclusive scan of cnt -> rowptr + zero cursor;
// blocks 1..9 = per-relation compact scans (block 9 = root identity).
__global__ __launch_bounds__(1024) void scan_combo(const int* __restrict__ cnt,
                                                   int* __restrict__ rowptr,
                                                   int* __restrict__ cursor,
                                                   const int* __restrict__ flag,
                                                   int* __restrict__ row_src,
                                                   int* __restrict__ pos_tab,
                                                   int* __restrict__ relcnt9) {
    __shared__ int wsum[16];
    __shared__ int carry;
    const int tid = threadIdx.x;
    const int lane = tid & 63;
    const int w = tid >> 6;

    if (blockIdx.x == 0) {
        if (tid == 0) carry = 0;
        const int nchunk = (kN + 1024) / 1024;
        for (int ch = 0; ch < nchunk; ++ch) {
            int idx = ch * 1024 + tid;
            int v = (idx < kN) ? cnt[idx] : 0;
            int s = v;
#pragma unroll
            for (int off = 1; off < 64; off <<= 1) {
                int t = __shfl_up(s, off, 64);
                if (lane >= off) s += t;
            }
            if (lane == 63) wsum[w] = s;
            __syncthreads();
            if (w == 0 && lane < 16) {
                int t = wsum[lane];
#pragma unroll
                for (int off = 1; off < 16; off <<= 1) {
                    int tt = __shfl_up(t, off, 64);
                    if (lane >= off) t += tt;
                }
                wsum[lane] = t;
            }
            __syncthreads();
            int wpre = (w > 0) ? wsum[w - 1] : 0;
            int incl = s + wpre + carry;
            int excl = incl - v;
            if (idx <= kN) rowptr[idx] = excl;
            if (idx < kN) cursor[idx] = 0;
            __syncthreads();
            if (tid == 1023) carry = incl;
            __syncthreads();
        }
        return;
    }

    const int rr = blockIdx.x - 1;      // 0..8
    if (rr == kR) {   // root range: identity
        for (int i = tid; i < kNpad; i += 1024) row_src[i] = i;
        if (tid == 0) relcnt9[0] = kN;
        return;
    }
    const int r = rr;
    const int base = kNpad * (r + 1);
    if (tid == 0) carry = 0;
    const int nchunk = (kN + 1023) / 1024;
    for (int ch = 0; ch < nchunk; ++ch) {
        int idx = ch * 1024 + tid;
        int v = (idx < kN) ? flag[r * kN + idx] : 0;
        int s = v;
#pragma unroll
        for (int off = 1; off < 64; off <<= 1) {
            int t = __shfl_up(s, off, 64);
            if (lane >= off) s += t;
        }
        if (lane == 63) wsum[w] = s;
        __syncthreads();
        if (w == 0 && lane < 16) {
            int t = wsum[lane];
#pragma unroll
            for (int off = 1; off < 16; off <<= 1) {
                int tt = __shfl_up(t, off, 64);
                if (lane >= off) t += tt;
            }
            wsum[lane] = t;
        }
        __syncthreads();
        int wpre = (w > 0) ? wsum[w - 1] : 0;
        int incl = s + wpre + carry;
        int excl = incl - v;
        if (idx < kN && v) {
            row_src[base + excl] = idx;
            pos_tab[r * kN + idx] = base + excl;
        }
        __syncthreads();
        if (tid == 1023) carry = incl;
        __syncthreads();
    }
    if (tid == 0) relcnt9[r + 1] = carry;
}

// erec = (y_c row << 3) | rel, CSR-grouped by dst.
__global__ void fill_edges(const int* __restrict__ src, const int* __restrict__ dst,
                           const int* __restrict__ etype, const int* __restrict__ rowptr,
                           int* __restrict__ cursor, const int* __restrict__ pos_tab,
                           int* __restrict__ erec) {
    int e = blockIdx.x * blockDim.x + threadIdx.x;
    if (e < kE) {
        int d = dst[e], r = etype[e], s = src[e];
        int pos = rowptr[d] + atomicAdd(&cursor[d], 1);
        erec[pos] = (pos_tab[r * kN + s] << 3) | r;
    }
}

// FUSED: x fp32 -> bf16 into ga[:,1024:2048]; zero both halves of pad rows.
__global__ void prep_ga(const float* __restrict__ x, u16* __restrict__ ga) {
    int row = blockIdx.x;
    int c = threadIdx.x << 2;
    if (row < kN) {
        float4 v = *reinterpret_cast<const float4*>(x + (size_t)row * kD + c);
        *reinterpret_cast<ushort4*>(ga + (size_t)row * kKz + kD + c) = f2bf4(v);
    } else {
        ushort4 z4;
        z4.x = 0; z4.y = 0; z4.z = 0; z4.w = 0;
        *reinterpret_cast<ushort4*>(ga + (size_t)row * kKz + c) = z4;
        *reinterpret_cast<ushort4*>(ga + (size_t)row * kKz + kD + c) = z4;
    }
}

// FUSED: all transposes in one launch, z-batched 1024x1024 squares.
__global__ void transpose_all(const float* __restrict__ root,
                              const float* __restrict__ weight,
                              const float* __restrict__ wgate,
                              u16* __restrict__ Bt9, u16* __restrict__ wg_t) {
    const int z = blockIdx.z;
    const float* S;
    u16* D;
    int ldD;
    if (z == 0)       { S = root;                              D = Bt9;                       ldD = kD; }
    else if (z <= 8)  { S = weight + (size_t)(z - 1) * kD * kD; D = Bt9 + (size_t)z * kD * kD; ldD = kD; }
    else              { S = wgate + (size_t)(z - 9) * kD * kD;  D = wg_t + (size_t)(z - 9) * kD; ldD = kKz; }
    __shared__ float t[32][33];
    int c0 = blockIdx.x * 32, r0 = blockIdx.y * 32;
    int x = threadIdx.x, y = threadIdx.y;   // block (32,8)
#pragma unroll
    for (int i = 0; i < 32; i += 8)
        t[y + i][x] = S[(size_t)(r0 + y + i) * kD + c0 + x];
    __syncthreads();
#pragma unroll
    for (int i = 0; i < 32; i += 8)
        D[(size_t)(c0 + y + i) * ldD + r0 + x] = f2bf(t[x][y + i]);
}

__device__ __forceinline__ void acc8_row(float* acc, uint4 v, float s) {
    const unsigned* u = &v.x;
#pragma unroll
    for (int q = 0; q < 4; ++q) {
        acc[2 * q]     += s * bf2f((u16)(u[q] & 0xffffu));
        acc[2 * q + 1] += s * bf2f((u16)(u[q] >> 16));
    }
}

// r16: aggregate rewidened to 128 threads x 16B/lane (uint4 row reads, G13
// sweet spot): halves per-edge instruction count, doubles bytes-in-flight
// per lane, smaller blocks -> more resident blocks/CU. Arithmetic identical
// (same edge order, fp32 accumulate). Parallel per-relation count kept.
__global__ __launch_bounds__(128) void aggregate(const u16* __restrict__ yc,
                                                 const float* __restrict__ bias,
                                                 const int* __restrict__ rowptr,
                                                 const int* __restrict__ erec,
                                                 u16* __restrict__ ga) {
    const int d = blockIdx.x;
    const int c = threadIdx.x << 3;           // 8 bf16 columns per thread
    const int e0 = rowptr[d], e1 = rowptr[d + 1];

    __shared__ int cc8[kR];
    __shared__ float rs[kR];
    if (threadIdx.x < kR) cc8[threadIdx.x] = 0;
    __syncthreads();
    if (threadIdx.x < 64) {
        for (int e = e0 + threadIdx.x; e < e1; e += 64)
            atomicAdd(&cc8[erec[e] & 7], 1);
    }
    __syncthreads();
    if (threadIdx.x < kR)
        rs[threadIdx.x] = 1.0f / fmaxf((float)cc8[threadIdx.x], 1.0f);
    __syncthreads();

    float acc[8];
    {
        uint4 rv = *reinterpret_cast<const uint4*>(yc + (size_t)d * kD + c);
        const unsigned* u = &rv.x;
        const float* bp = bias + c;
#pragma unroll
        for (int q = 0; q < 4; ++q) {
            acc[2 * q]     = bf2f((u16)(u[q] & 0xffffu)) + bp[2 * q];
            acc[2 * q + 1] = bf2f((u16)(u[q] >> 16)) + bp[2 * q + 1];
        }
    }

    int e = e0;
    for (; e + 3 < e1; e += 4) {
        int r0_ = erec[e], r1_ = erec[e + 1], r2_ = erec[e + 2], r3_ = erec[e + 3];
        uint4 v0 = *reinterpret_cast<const uint4*>(yc + (size_t)(r0_ >> 3) * kD + c);
        uint4 v1 = *reinterpret_cast<const uint4*>(yc + (size_t)(r1_ >> 3) * kD + c);
        uint4 v2 = *reinterpret_cast<const uint4*>(yc + (size_t)(r2_ >> 3) * kD + c);
        uint4 v3 = *reinterpret_cast<const uint4*>(yc + (size_t)(r3_ >> 3) * kD + c);
        acc8_row(acc, v0, rs[r0_ & 7]);
        acc8_row(acc, v1, rs[r1_ & 7]);
        acc8_row(acc, v2, rs[r2_ & 7]);
        acc8_row(acc, v3, rs[r3_ & 7]);
    }
    for (; e < e1; ++e) {
        int rec = erec[e];
        uint4 v = *reinterpret_cast<const uint4*>(yc + (size_t)(rec >> 3) * kD + c);
        acc8_row(acc, v, rs[rec & 7]);
    }

    ushort4 o0, o1;
    o0.x = f2bf(acc[0]); o0.y = f2bf(acc[1]); o0.z = f2bf(acc[2]); o0.w = f2bf(acc[3]);
    o1.x = f2bf(acc[4]); o1.y = f2bf(acc[5]); o1.z = f2bf(acc[6]); o1.w = f2bf(acc[7]);
    *reinterpret_cast<ushort4*>(ga + (size_t)d * kKz + c) = o0;
    *reinterpret_cast<ushort4*>(ga + (size_t)d * kKz + c + 4) = o1;
}

// GEMM1 (compacted): y_c[grow] = x_bf[row_src[grow]] @ W_{rel(grow)}^T.
// FROZEN at r12 (best: 181.5 us, 699 TF, MfmaUtil 29.7). Deep-pipeline
// 4-phase, 256x256/BK=64/8-wave/dbuf, whole-tile vmcnt(6) guard at ph0,
// pre-barrier ds_read hoisting, fences flanking barriers, T2 swizzle, T5
// setprio.
__global__ __launch_bounds__(512, 2) void gemm_compact(
    const u16* __restrict__ xb, int ldx,
    const u16* __restrict__ Bt9,
    const int* __restrict__ row_src, const int* __restrict__ relcnt9,
    u16* __restrict__ yc)
{
    const int t0 = blockIdx.y;
    const int relidx = t0 / 40;
    const int lt = t0 - relidx * 40;
    if (lt * 256 >= relcnt9[relidx]) return;   // uniform early-exit (before barriers)

    __shared__ u16 sA[2][256 * 64];   // 64KB
    __shared__ u16 sB[2][256 * 64];   // 64KB

    const int tid = threadIdx.x;
    const int wave = tid >> 6;
    const int lane = tid & 63;

    const int row0 = t0 * 256;
    const int col0 = blockIdx.x * 256;

    const int s_row = tid >> 3;                                   // 0..63
    const int s_src = ((tid & 7) ^ (s_row & 7)) * 8;              // swizzled source col
    const int wbase = wave * 512;                                 // LDS u16 base per wave

    const u16* gA[4];
    const u16* gB[4];
#pragma unroll
    for (int q = 0; q < 4; ++q) {
        gA[q] = xb + (size_t)row_src[row0 + q * 64 + s_row] * ldx + s_src;
        gB[q] = Bt9 + (size_t)(relidx * kD + col0 + q * 64 + s_row) * kD + s_src;
    }

    auto stageA = [&](int b, int h) {
        u16* dA = &sA[b][0];
#pragma unroll
        for (int q = 2 * h; q < 2 * h + 2; ++q) {
            __builtin_amdgcn_global_load_lds(GLB(gA[q]), LDSP(dA + q * 4096 + wbase), 16, 0, 0);
            gA[q] += 64;
        }
    };
    auto stageB = [&](int b, int h) {
        u16* dB = &sB[b][0];
#pragma unroll
        for (int q = 2 * h; q < 2 * h + 2; ++q) {
            __builtin_amdgcn_global_load_lds(GLB(gB[q]), LDSP(dB + q * 4096 + wbase), 16, 0, 0);
            gB[q] += 64;
        }
    };

    const int wm = (wave >> 2) * 128;      // 0 / 128
    const int wn = (wave & 3) * 64;        // 0..192
    const int fm = lane & 15;
    const int g4 = lane >> 4;              // 0..3
    const int pc0 = ((g4) ^ (fm & 7)) * 8;        // ks=0 physical chunk (u16 off)
    const int pc1 = ((4 | g4) ^ (fm & 7)) * 8;    // ks=1

    f32x4 zf = {0.0f, 0.0f, 0.0f, 0.0f};
    f32x4 acc[8][4];
#pragma unroll
    for (int i = 0; i < 8; ++i)
#pragma unroll
        for (int j = 0; j < 4; ++j) acc[i][j] = zf;

    constexpr int T = kD / 64;   // 16 K-tiles
    // prologue stage order: A0(0) A1(0) B0(0) B1(0) -> buf0; B0(1) B1(1) -> buf1
    stageA(0, 0); stageA(0, 1); stageB(0, 0); stageB(0, 1);
    stageB(1, 0); stageB(1, 1);

    bf16x8 af[8], bfl[4], bfh[4];

    for (int t = 0; t < T; ++t) {
        const int cb = t & 1, nb = cb ^ 1;
        const bool pf1 = (t + 1 < T);
        const bool pf2 = (t + 2 < T);
        const u16* cA = sA[cb];
        const u16* cB = sB[cb];

        // ========= ph0: stage A0(t+1); whole-tile guard; reads; MFMA Q00
        if (pf1) stageA(nb, 0);
        if (t < T - 1) asm volatile("s_waitcnt vmcnt(6)" ::: "memory");
        else           asm volatile("s_waitcnt vmcnt(0)" ::: "memory");
        __builtin_amdgcn_s_barrier();
        asm volatile("" ::: "memory");
#pragma unroll
        for (int i = 0; i < 4; ++i) {
            af[2 * i]     = *reinterpret_cast<const bf16x8*>(&cA[(wm + i * 16 + fm) * 64 + pc0]);
            af[2 * i + 1] = *reinterpret_cast<const bf16x8*>(&cA[(wm + i * 16 + fm) * 64 + pc1]);
        }
#pragma unroll
        for (int j = 0; j < 2; ++j) {
            bfl[2 * j]     = *reinterpret_cast<const bf16x8*>(&cB[(wn + j * 16 + fm) * 64 + pc0]);
            bfl[2 * j + 1] = *reinterpret_cast<const bf16x8*>(&cB[(wn + j * 16 + fm) * 64 + pc1]);
        }
        __builtin_amdgcn_s_setprio(1);
#pragma unroll
        for (int i = 0; i < 4; ++i)
#pragma unroll
            for (int j = 0; j < 2; ++j) {
                acc[i][j] = __builtin_amdgcn_mfma_f32_16x16x32_bf16(bfl[2 * j], af[2 * i], acc[i][j], 0, 0, 0);
                acc[i][j] = __builtin_amdgcn_mfma_f32_16x16x32_bf16(bfl[2 * j + 1], af[2 * i + 1], acc[i][j], 0, 0, 0);
            }
        __builtin_amdgcn_s_setprio(0);

        // ========= ph1: reads B1-range (pre-barrier); stage A1(t+1); MFMA Q01
#pragma unroll
        for (int j = 0; j < 2; ++j) {
            bfh[2 * j]     = *reinterpret_cast<const bf16x8*>(&cB[(wn + 32 + j * 16 + fm) * 64 + pc0]);
            bfh[2 * j + 1] = *reinterpret_cast<const bf16x8*>(&cB[(wn + 32 + j * 16 + fm) * 64 + pc1]);
        }
        if (pf1) stageA(nb, 1);
        asm volatile("" ::: "memory");
        __builtin_amdgcn_s_barrier();
        asm volatile("" ::: "memory");
        __builtin_amdgcn_s_setprio(1);
#pragma unroll
        for (int i = 0; i < 4; ++i)
#pragma unroll
            for (int j = 0; j < 2; ++j) {
                acc[i][2 + j] = __builtin_amdgcn_mfma_f32_16x16x32_bf16(bfh[2 * j], af[2 * i], acc[i][2 + j], 0, 0, 0);
                acc[i][2 + j] = __builtin_amdgcn_mfma_f32_16x16x32_bf16(bfh[2 * j + 1], af[2 * i + 1], acc[i][2 + j], 0, 0, 0);
            }
        __builtin_amdgcn_s_setprio(0);

        // ========= ph2: reads A hi-rows (pre-barrier); MFMA Q11
#pragma unroll
        for (int i = 0; i < 4; ++i) {
            af[2 * i]     = *reinterpret_cast<const bf16x8*>(&cA[(wm + 64 + i * 16 + fm) * 64 + pc0]);
            af[2 * i + 1] = *reinterpret_cast<const bf16x8*>(&cA[(wm + 64 + i * 16 + fm) * 64 + pc1]);
        }
        asm volatile("" ::: "memory");
        __builtin_amdgcn_s_barrier();
        asm volatile("" ::: "memory");
        __builtin_amdgcn_s_setprio(1);
#pragma unroll
        for (int i = 0; i < 4; ++i)
#pragma unroll
            for (int j = 0; j < 2; ++j) {
                acc[4 + i][2 + j] = __builtin_amdgcn_mfma_f32_16x16x32_bf16(bfh[2 * j], af[2 * i], acc[4 + i][2 + j], 0, 0, 0);
                acc[4 + i][2 + j] = __builtin_amdgcn_mfma_f32_16x16x32_bf16(bfh[2 * j + 1], af[2 * i + 1], acc[4 + i][2 + j], 0, 0, 0);
            }
        __builtin_amdgcn_s_setprio(0);

        // ========= ph3: stage B0(t+2)+B1(t+2); MFMA Q10 (register reuse)
        if (pf2) { stageB(cb, 0); stageB(cb, 1); }
        asm volatile("" ::: "memory");
        __builtin_amdgcn_s_barrier();
        asm volatile("" ::: "memory");
        __builtin_amdgcn_s_setprio(1);
#pragma unroll
        for (int i = 0; i < 4; ++i)
#pragma unroll
            for (int j = 0; j < 2; ++j) {
                acc[4 + i][j] = __builtin_amdgcn_mfma_f32_16x16x32_bf16(bfl[2 * j], af[2 * i], acc[4 + i][j], 0, 0, 0);
                acc[4 + i][j] = __builtin_amdgcn_mfma_f32_16x16x32_bf16(bfl[2 * j + 1], af[2 * i + 1], acc[4 + i][j], 0, 0, 0);
            }
        __builtin_amdgcn_s_setprio(0);
    }

    // Transposed C/D: row = wm + i*16 + fm, col = wn + j*16 + g4*4 + reg
    const int cq = g4 * 4;
#pragma unroll
    for (int i = 0; i < 8; ++i) {
        int row = row0 + wm + i * 16 + fm;   // y_c fully padded: no guard
#pragma unroll
        for (int j = 0; j < 4; ++j) {
            int col = col0 + wn + j * 16 + cq;
            f32x4 v = acc[i][j];
            ushort4 o;
            o.x = f2bf(v[0]); o.y = f2bf(v[1]); o.z = f2bf(v[2]); o.w = f2bf(v[3]);
            *reinterpret_cast<ushort4*>(yc + (size_t)row * kD + col) = o;
        }
    }
}

// GEMM2: REVERTED to r14 structure (128x128, BK=32, 4 waves, 3-stage
// counted-vmcnt, 48KB LDS -> 3 blocks/CU). r15's deep-pipeline port
// regressed +38us: it traded 3->2 blocks/CU occupancy (TLP that was doing
// real latency hiding) for pipeline depth, and halved the per-phase MFMA
// cluster. Lesson: occupancy and source-pipelining draw on the same budget.
__global__ __launch_bounds__(256, 3) void gemm_mfma_gate(
    const u16* __restrict__ A, int lda,
    const u16* __restrict__ Bt, int ldb, int K,
    int M, const float* __restrict__ bias,
    float* __restrict__ Cf, const u16* __restrict__ uga, const float* __restrict__ xo)
{
    __shared__ u16 sA[3][128 * 32];
    __shared__ u16 sB[3][128 * 32];

    const int tid = threadIdx.x;
    const int wave = tid >> 6;
    const int lane = tid & 63;

    constexpr int GX = kD / 128;      // 8 col tiles
    constexpr int GY = kNpad / 128;   // 80 row tiles
    const int lin = blockIdx.y * GX + blockIdx.x;
    const int xcd = lin & 7;          // default XCD of this block
    const int pos = lin >> 3;         // 0..79 within this XCD
    const int ty = xcd * (GY / 8) + (pos >> 3);
    const int tx = pos & 7;

    const int row0 = ty * 128;
    const int col0 = tx * 128;

    const int srow = wave * 16 + (lane >> 2);
    const int scol = (((lane & 3) ^ ((srow >> 1) & 3)) * 8);     // swizzled source chunk

    const u16* gA0 = A + (size_t)(row0 + srow) * lda + scol;
    const u16* gA1 = A + (size_t)(row0 + 64 + srow) * lda + scol;
    const u16* gB0 = Bt + (size_t)(col0 + srow) * ldb + scol;
    const u16* gB1 = Bt + (size_t)(col0 + 64 + srow) * ldb + scol;

    const int lof0 = (wave * 16) * 32;
    const int lof1 = (64 + wave * 16) * 32;

    const int mq = (wave >> 1) * 64;
    const int nq = (wave & 1) * 64;
    const int fm = lane & 15;
    const int fkx = (((lane >> 4) ^ ((fm >> 1) & 3))) * 8;       // swizzled read chunk

    f32x4 zf = {0.0f, 0.0f, 0.0f, 0.0f};
    f32x4 acc[4][4];
#pragma unroll
    for (int i = 0; i < 4; ++i)
#pragma unroll
        for (int j = 0; j < 4; ++j) acc[i][j] = zf;

    auto stage = [&](int s) {
        __builtin_amdgcn_global_load_lds(GLB(gA0), LDSP(sA[s] + lof0), 16, 0, 0);
        __builtin_amdgcn_global_load_lds(GLB(gA1), LDSP(sA[s] + lof1), 16, 0, 0);
        __builtin_amdgcn_global_load_lds(GLB(gB0), LDSP(sB[s] + lof0), 16, 0, 0);
        __builtin_amdgcn_global_load_lds(GLB(gB1), LDSP(sB[s] + lof1), 16, 0, 0);
        gA0 += 32; gA1 += 32; gB0 += 32; gB1 += 32;
    };

    const int T = K >> 5;   // 64 K-steps
    stage(0);
    stage(1);

    int s = 0;
    for (int t = 0; t < T; ++t) {
        if (t + 2 < T) {
            stage(s == 0 ? 2 : (s - 1));          // (t+2)%3
            asm volatile("s_waitcnt vmcnt(8)" ::: "memory");
        } else if (t + 1 < T) {
            asm volatile("s_waitcnt vmcnt(4)" ::: "memory");
        } else {
            asm volatile("s_waitcnt vmcnt(0)" ::: "memory");
        }
        __builtin_amdgcn_s_barrier();
        asm volatile("" ::: "memory");

        const u16* cA = sA[s];
        const u16* cB = sB[s];
        bf16x8 af[4], bfr[4];
#pragma unroll
        for (int i = 0; i < 4; ++i)
            af[i] = *reinterpret_cast<const bf16x8*>(&cA[(mq + i * 16 + fm) * 32 + fkx]);
#pragma unroll
        for (int j = 0; j < 4; ++j)
            bfr[j] = *reinterpret_cast<const bf16x8*>(&cB[(nq + j * 16 + fm) * 32 + fkx]);
#pragma unroll
        for (int i = 0; i < 4; ++i)
#pragma unroll
            for (int j = 0; j < 4; ++j)
                acc[i][j] = __builtin_amdgcn_mfma_f32_16x16x32_bf16(bfr[j], af[i], acc[i][j], 0, 0, 0);

        asm volatile("" ::: "memory");
        __builtin_amdgcn_s_barrier();
        s = (s == 2) ? 0 : (s + 1);
    }

    const int cq = (lane >> 4) * 4;
#pragma unroll
    for (int i = 0; i < 4; ++i) {
        int row = row0 + mq + i * 16 + fm;
        if (row >= M) continue;
#pragma unroll
        for (int j = 0; j < 4; ++j) {
            int col = col0 + nq + j * 16 + cq;
            f32x4 v = acc[i][j];
            float4 bv = *reinterpret_cast<const float4*>(bias + col);
            v[0] += bv.x; v[1] += bv.y; v[2] += bv.z; v[3] += bv.w;
            ushort4 ur = *reinterpret_cast<const ushort4*>(uga + (size_t)row * kKz + col);
            float4 xr = *reinterpret_cast<const float4*>(xo + (size_t)row * kD + col);
            float4 h;
            h.x = tanhf(bf2f(ur.x)) * v[0] + xr.x * (1.0f - v[0]);
            h.y = tanhf(bf2f(ur.y)) * v[1] + xr.y * (1.0f - v[1]);
            h.z = tanhf(bf2f(ur.z)) * v[2] + xr.z * (1.0f - v[2]);
            h.w = tanhf(bf2f(ur.w)) * v[3] + xr.w * (1.0f - v[3]);
            *reinterpret_cast<float4*>(Cf + (size_t)row * kD + col) = h;
        }
    }
}

extern "C" void kernel_launch(void* const* d_in, const int* in_sizes, int n_in,
                              void* d_out, int out_size, void* d_ws, size_t ws_size,
                              hipStream_t stream) {
    (void)in_sizes; (void)n_in; (void)out_size; (void)ws_size;

    const float* x     = (const float*)d_in[0];
    const int* eidx    = (const int*)d_in[1];
    const int* etype   = (const int*)d_in[2];
    const float* weight= (const float*)d_in[3];
    const float* root  = (const float*)d_in[4];
    const float* bias  = (const float*)d_in[5];
    const float* wgate = (const float*)d_in[6];
    const float* bgate = (const float*)d_in[7];
    float* out = (float*)d_out;

    const int* src = eidx;
    const int* dst = eidx + kE;

    // ---- workspace ----
    char* ws = (char*)d_ws;
    size_t off = 0;
    u16* yc   = (u16*)(ws + off);    off += (size_t)kCrows * kD * 2;   // 188.7 MB
    u16* ga   = (u16*)(ws + off);    off += (size_t)kNpad * kKz * 2;   //  41.9 MB
    u16* Bt9  = (u16*)(ws + off);    off += (size_t)(kR + 1) * kD * kD * 2; // 18.9 MB
    u16* wg_t = (u16*)(ws + off);    off += (size_t)kD * kKz * 2;      //   4.2 MB
    int* cntd    = (int*)(ws + off); off += (size_t)kN * 4;            // 10000
    int* flag    = (int*)(ws + off); off += (size_t)kR * kN * 4;       // 80000
    int* row_src = (int*)(ws + off); off += (size_t)kCrows * 4;        // 92160
    int* pos_tab = (int*)(ws + off); off += (size_t)kR * kN * 4;
    int* rowp    = (int*)(ws + off); off += (size_t)(kN + 16) * 4;
    int* curs    = (int*)(ws + off); off += (size_t)kN * 4;
    int* erec    = (int*)(ws + off); off += (size_t)kE * 4;
    int* relcnt9 = (int*)(ws + off); off += 16 * 4;

    // zero cntd+flag+row_src in one pass (contiguous, 182160 ints)
    zero16<<<180, 256, 0, stream>>>((uint4*)cntd, (long)(kN + kR * kN + kCrows) / 4);

    mark_edges<<<(kE + 255) / 256, 256, 0, stream>>>(src, dst, etype, cntd, flag);

    // fused: block 0 = rowptr scan, blocks 1..9 = per-relation compaction
    scan_combo<<<kR + 2, 1024, 0, stream>>>(cntd, rowp, curs, flag, row_src,
                                            pos_tab, relcnt9);

    fill_edges<<<(kE + 255) / 256, 256, 0, stream>>>(src, dst, etype, rowp, curs,
                                                     pos_tab, erec);

    // fused: x -> bf16 into ga[:,1024:2048] + zero pad rows [kN,kNpad)
    prep_ga<<<kNpad, 256, 0, stream>>>(x, ga);

    // fused: root/weight -> Bt9, wgate -> wg_t, one launch (z=0..10)
    {
        dim3 b(32, 8);
        transpose_all<<<dim3(kD / 32, kD / 32, 11), b, 0, stream>>>(root, weight,
                                                                    wgate, Bt9, wg_t);
    }

    // GEMM1 (compacted): y_c = gathered x rows @ per-relation W
    dim3 g1(kD / 256, kCrows / 256);   // 4 x 360, ~2/3 exit early
    gemm_compact<<<g1, 512, 0, stream>>>(ga + kD, kKz, Bt9, row_src, relcnt9, yc);

    // aggregate: u -> ga[:,0:1024] (bf16)
    aggregate<<<kN, 128, 0, stream>>>(yc, bias, rowp, erec, ga);

    // GEMM2: z = ga @ wg_t + b_gate; h = tanh(u)*z + x*(1-z) -> out
    dim3 g2(kD / 128, kNpad / 128);    // 8 x 80
    gemm_mfma_gate<<<g2, 256, 0, stream>>>(ga, kKz, wg_t, kKz, kKz, kN, bgate, out, ga, x);
}

// Round 17
// 440.398 us; speedup vs baseline: 1.0926x; 1.0017x over previous
//
#include <hip/hip_runtime.h>
#include <math.h>

typedef unsigned short u16;
typedef __attribute__((ext_vector_type(8))) short bf16x8;   // 8 bf16 = 4 VGPRs
typedef __attribute__((ext_vector_type(4))) float f32x4;

static constexpr int kN = 10000;
static constexpr int kNpad = 10240;       // 40 * 256 rows per relation range
static constexpr int kD = 1024;
static constexpr int kR = 8;
static constexpr int kE = 80000;
static constexpr int kKz = 2 * kD;        // 2048 : [u | x]
static constexpr int kCrows = kNpad * (kR + 1);  // 92160 compact y_c rows (worst case)

#define GLB(p) ((const __attribute__((address_space(1))) unsigned int*)(const void*)(p))
#define LDSP(p) ((__attribute__((address_space(3))) unsigned int*)(p))

__device__ __forceinline__ u16 f2bf(float f) {
    union { float f; unsigned int i; } c; c.f = f;
    unsigned int u = c.i;
    return (u16)((u + 0x7FFFu + ((u >> 16) & 1u)) >> 16);   // RNE
}
__device__ __forceinline__ float bf2f(u16 u) {
    union { unsigned int i; float f; } c; c.i = ((unsigned int)u) << 16;
    return c.f;
}
__device__ __forceinline__ ushort4 f2bf4(float4 v) {
    ushort4 o; o.x = f2bf(v.x); o.y = f2bf(v.y); o.z = f2bf(v.z); o.w = f2bf(v.w);
    return o;
}

__global__ void zero16(uint4* __restrict__ p, long n16) {
    long i = (long)blockIdx.x * blockDim.x + threadIdx.x;
    long st = (long)gridDim.x * blockDim.x;
    uint4 z = make_uint4(0, 0, 0, 0);
    for (; i < n16; i += st) p[i] = z;
}

// Per edge: histogram dst (for CSR) and flag (rel, src) presence.
__global__ void mark_edges(const int* __restrict__ src, const int* __restrict__ dst,
                           const int* __restrict__ etype,
                           int* __restrict__ cntd, int* __restrict__ flag) {
    int e = blockIdx.x * blockDim.x + threadIdx.x;
    if (e < kE) {
        atomicAdd(&cntd[dst[e]], 1);
        flag[etype[e] * kN + src[e]] = 1;   // idempotent plain store
    }
}

// FUSED: block 0 = exclusive scan of cnt -> rowptr + zero cursor;
// blocks 1..9 = per-relation compact scans (block 9 = root identity).
__global__ __launch_bounds__(1024) void scan_combo(const int* __restrict__ cnt,
                                                   int* __restrict__ rowptr,
                                                   int* __restrict__ cursor,
                                                   const int* __restrict__ flag,
                                                   int* __restrict__ row_src,
                                                   int* __restrict__ pos_tab,
                                                   int* __restrict__ relcnt9) {
    __shared__ int wsum[16];
    __shared__ int carry;
    const int tid = threadIdx.x;
    const int lane = tid & 63;
    const int w = tid >> 6;

    if (blockIdx.x == 0) {
        if (tid == 0) carry = 0;
        const int nchunk = (kN + 1024) / 1024;
        for (int ch = 0; ch < nchunk; ++ch) {
            int idx = ch * 1024 + tid;
            int v = (idx < kN) ? cnt[idx] : 0;
            int s = v;
#pragma unroll
            for (int off = 1; off < 64; off <<= 1) {
                int t = __shfl_up(s, off, 64);
                if (lane >= off) s += t;
            }
            if (lane == 63) wsum[w] = s;
            __syncthreads();
            if (w == 0 && lane < 16) {
                int t = wsum[lane];
#pragma unroll
                for (int off = 1; off < 16; off <<= 1) {
                    int tt = __shfl_up(t, off, 64);
                    if (lane >= off) t += tt;
                }
                wsum[lane] = t;
            }
            __syncthreads();
            int wpre = (w > 0) ? wsum[w - 1] : 0;
            int incl = s + wpre + carry;
            int excl = incl - v;
            if (idx <= kN) rowptr[idx] = excl;
            if (idx < kN) cursor[idx] = 0;
            __syncthreads();
            if (tid == 1023) carry = incl;
            __syncthreads();
        }
        return;
    }

    const int rr = blockIdx.x - 1;      // 0..8
    if (rr == kR) {   // root range: identity
        for (int i = tid; i < kNpad; i += 1024) row_src[i] = i;
        if (tid == 0) relcnt9[0] = kN;
        return;
    }
    const int r = rr;
    const int base = kNpad * (r + 1);
    if (tid == 0) carry = 0;
    const int nchunk = (kN + 1023) / 1024;
    for (int ch = 0; ch < nchunk; ++ch) {
        int idx = ch * 1024 + tid;
        int v = (idx < kN) ? flag[r * kN + idx] : 0;
        int s = v;
#pragma unroll
        for (int off = 1; off < 64; off <<= 1) {
            int t = __shfl_up(s, off, 64);
            if (lane >= off) s += t;
        }
        if (lane == 63) wsum[w] = s;
        __syncthreads();
        if (w == 0 && lane < 16) {
            int t = wsum[lane];
#pragma unroll
            for (int off = 1; off < 16; off <<= 1) {
                int tt = __shfl_up(t, off, 64);
                if (lane >= off) t += tt;
            }
            wsum[lane] = t;
        }
        __syncthreads();
        int wpre = (w > 0) ? wsum[w - 1] : 0;
        int incl = s + wpre + carry;
        int excl = incl - v;
        if (idx < kN && v) {
            row_src[base + excl] = idx;
            pos_tab[r * kN + idx] = base + excl;
        }
        __syncthreads();
        if (tid == 1023) carry = incl;
        __syncthreads();
    }
    if (tid == 0) relcnt9[r + 1] = carry;
}

// erec = (y_c row << 3) | rel, CSR-grouped by dst.
__global__ void fill_edges(const int* __restrict__ src, const int* __restrict__ dst,
                           const int* __restrict__ etype, const int* __restrict__ rowptr,
                           int* __restrict__ cursor, const int* __restrict__ pos_tab,
                           int* __restrict__ erec) {
    int e = blockIdx.x * blockDim.x + threadIdx.x;
    if (e < kE) {
        int d = dst[e], r = etype[e], s = src[e];
        int pos = rowptr[d] + atomicAdd(&cursor[d], 1);
        erec[pos] = (pos_tab[r * kN + s] << 3) | r;
    }
}

// FUSED: x fp32 -> bf16 into ga[:,1024:2048]; zero both halves of pad rows.
__global__ void prep_ga(const float* __restrict__ x, u16* __restrict__ ga) {
    int row = blockIdx.x;
    int c = threadIdx.x << 2;
    if (row < kN) {
        float4 v = *reinterpret_cast<const float4*>(x + (size_t)row * kD + c);
        *reinterpret_cast<ushort4*>(ga + (size_t)row * kKz + kD + c) = f2bf4(v);
    } else {
        ushort4 z4;
        z4.x = 0; z4.y = 0; z4.z = 0; z4.w = 0;
        *reinterpret_cast<ushort4*>(ga + (size_t)row * kKz + c) = z4;
        *reinterpret_cast<ushort4*>(ga + (size_t)row * kKz + kD + c) = z4;
    }
}

// FUSED: all transposes in one launch, z-batched 1024x1024 squares.
__global__ void transpose_all(const float* __restrict__ root,
                              const float* __restrict__ weight,
                              const float* __restrict__ wgate,
                              u16* __restrict__ Bt9, u16* __restrict__ wg_t) {
    const int z = blockIdx.z;
    const float* S;
    u16* D;
    int ldD;
    if (z == 0)       { S = root;                              D = Bt9;                       ldD = kD; }
    else if (z <= 8)  { S = weight + (size_t)(z - 1) * kD * kD; D = Bt9 + (size_t)z * kD * kD; ldD = kD; }
    else              { S = wgate + (size_t)(z - 9) * kD * kD;  D = wg_t + (size_t)(z - 9) * kD; ldD = kKz; }
    __shared__ float t[32][33];
    int c0 = blockIdx.x * 32, r0 = blockIdx.y * 32;
    int x = threadIdx.x, y = threadIdx.y;   // block (32,8)
#pragma unroll
    for (int i = 0; i < 32; i += 8)
        t[y + i][x] = S[(size_t)(r0 + y + i) * kD + c0 + x];
    __syncthreads();
#pragma unroll
    for (int i = 0; i < 32; i += 8)
        D[(size_t)(c0 + y + i) * ldD + r0 + x] = f2bf(t[x][y + i]);
}

__device__ __forceinline__ void acc8_row(float* acc, uint4 v, float s) {
    const unsigned* u = &v.x;
#pragma unroll
    for (int q = 0; q < 4; ++q) {
        acc[2 * q]     += s * bf2f((u16)(u[q] & 0xffffu));
        acc[2 * q + 1] += s * bf2f((u16)(u[q] >> 16));
    }
}

// r17: aggregate processes TWO dst rows per block (256 thr, 128/row,
// per-half LDS count tables). Halves block count 10000->5000 (less dispatch
// overhead) and doubles independent memory streams per CU in the
// latency-bound count phase. Arithmetic identical (same edge order, fp32
// accumulate). 16B/lane uint4 reads kept from r16.
__global__ __launch_bounds__(256) void aggregate(const u16* __restrict__ yc,
                                                 const float* __restrict__ bias,
                                                 const int* __restrict__ rowptr,
                                                 const int* __restrict__ erec,
                                                 u16* __restrict__ ga) {
    const int half = threadIdx.x >> 7;          // 0 or 1
    const int d = blockIdx.x * 2 + half;        // dst row (kN even -> d < kN)
    const int lt = threadIdx.x & 127;
    const int c = lt << 3;                      // 8 bf16 columns per thread
    const int e0 = rowptr[d], e1 = rowptr[d + 1];

    __shared__ int cc8[2][kR];
    __shared__ float rs[2][kR];
    if (lt < kR) cc8[half][lt] = 0;
    __syncthreads();
    if (lt < 64) {
        for (int e = e0 + lt; e < e1; e += 64)
            atomicAdd(&cc8[half][erec[e] & 7], 1);
    }
    __syncthreads();
    if (lt < kR)
        rs[half][lt] = 1.0f / fmaxf((float)cc8[half][lt], 1.0f);
    __syncthreads();

    float acc[8];
    {
        uint4 rv = *reinterpret_cast<const uint4*>(yc + (size_t)d * kD + c);
        const unsigned* u = &rv.x;
        const float* bp = bias + c;
#pragma unroll
        for (int q = 0; q < 4; ++q) {
            acc[2 * q]     = bf2f((u16)(u[q] & 0xffffu)) + bp[2 * q];
            acc[2 * q + 1] = bf2f((u16)(u[q] >> 16)) + bp[2 * q + 1];
        }
    }

    int e = e0;
    for (; e + 3 < e1; e += 4) {
        int r0_ = erec[e], r1_ = erec[e + 1], r2_ = erec[e + 2], r3_ = erec[e + 3];
        uint4 v0 = *reinterpret_cast<const uint4*>(yc + (size_t)(r0_ >> 3) * kD + c);
        uint4 v1 = *reinterpret_cast<const uint4*>(yc + (size_t)(r1_ >> 3) * kD + c);
        uint4 v2 = *reinterpret_cast<const uint4*>(yc + (size_t)(r2_ >> 3) * kD + c);
        uint4 v3 = *reinterpret_cast<const uint4*>(yc + (size_t)(r3_ >> 3) * kD + c);
        acc8_row(acc, v0, rs[half][r0_ & 7]);
        acc8_row(acc, v1, rs[half][r1_ & 7]);
        acc8_row(acc, v2, rs[half][r2_ & 7]);
        acc8_row(acc, v3, rs[half][r3_ & 7]);
    }
    for (; e < e1; ++e) {
        int rec = erec[e];
        uint4 v = *reinterpret_cast<const uint4*>(yc + (size_t)(rec >> 3) * kD + c);
        acc8_row(acc, v, rs[half][rec & 7]);
    }

    ushort4 o0, o1;
    o0.x = f2bf(acc[0]); o0.y = f2bf(acc[1]); o0.z = f2bf(acc[2]); o0.w = f2bf(acc[3]);
    o1.x = f2bf(acc[4]); o1.y = f2bf(acc[5]); o1.z = f2bf(acc[6]); o1.w = f2bf(acc[7]);
    *reinterpret_cast<ushort4*>(ga + (size_t)d * kKz + c) = o0;
    *reinterpret_cast<ushort4*>(ga + (size_t)d * kKz + c + 4) = o1;
}

// GEMM1 (compacted): y_c[grow] = x_bf[row_src[grow]] @ W_{rel(grow)}^T.
// FROZEN at r12 (best: 181.5 us, 699 TF, MfmaUtil 29.7). Deep-pipeline
// 4-phase, 256x256/BK=64/8-wave/dbuf, whole-tile vmcnt(6) guard at ph0,
// pre-barrier ds_read hoisting, fences flanking barriers, T2 swizzle, T5
// setprio. Structural ceiling: 1 blk/CU (128KB LDS) barrier convoys +
// near-ideal FETCH (206 vs 194 MB) leave no schedule or traffic lever;
// a 3rd pipeline buffer would need 192KB > 160KB LDS.
__global__ __launch_bounds__(512, 2) void gemm_compact(
    const u16* __restrict__ xb, int ldx,
    const u16* __restrict__ Bt9,
    const int* __restrict__ row_src, const int* __restrict__ relcnt9,
    u16* __restrict__ yc)
{
    const int t0 = blockIdx.y;
    const int relidx = t0 / 40;
    const int lt = t0 - relidx * 40;
    if (lt * 256 >= relcnt9[relidx]) return;   // uniform early-exit (before barriers)

    __shared__ u16 sA[2][256 * 64];   // 64KB
    __shared__ u16 sB[2][256 * 64];   // 64KB

    const int tid = threadIdx.x;
    const int wave = tid >> 6;
    const int lane = tid & 63;

    const int row0 = t0 * 256;
    const int col0 = blockIdx.x * 256;

    const int s_row = tid >> 3;                                   // 0..63
    const int s_src = ((tid & 7) ^ (s_row & 7)) * 8;              // swizzled source col
    const int wbase = wave * 512;                                 // LDS u16 base per wave

    const u16* gA[4];
    const u16* gB[4];
#pragma unroll
    for (int q = 0; q < 4; ++q) {
        gA[q] = xb + (size_t)row_src[row0 + q * 64 + s_row] * ldx + s_src;
        gB[q] = Bt9 + (size_t)(relidx * kD + col0 + q * 64 + s_row) * kD + s_src;
    }

    auto stageA = [&](int b, int h) {
        u16* dA = &sA[b][0];
#pragma unroll
        for (int q = 2 * h; q < 2 * h + 2; ++q) {
            __builtin_amdgcn_global_load_lds(GLB(gA[q]), LDSP(dA + q * 4096 + wbase), 16, 0, 0);
            gA[q] += 64;
        }
    };
    auto stageB = [&](int b, int h) {
        u16* dB = &sB[b][0];
#pragma unroll
        for (int q = 2 * h; q < 2 * h + 2; ++q) {
            __builtin_amdgcn_global_load_lds(GLB(gB[q]), LDSP(dB + q * 4096 + wbase), 16, 0, 0);
            gB[q] += 64;
        }
    };

    const int wm = (wave >> 2) * 128;      // 0 / 128
    const int wn = (wave & 3) * 64;        // 0..192
    const int fm = lane & 15;
    const int g4 = lane >> 4;              // 0..3
    const int pc0 = ((g4) ^ (fm & 7)) * 8;        // ks=0 physical chunk (u16 off)
    const int pc1 = ((4 | g4) ^ (fm & 7)) * 8;    // ks=1

    f32x4 zf = {0.0f, 0.0f, 0.0f, 0.0f};
    f32x4 acc[8][4];
#pragma unroll
    for (int i = 0; i < 8; ++i)
#pragma unroll
        for (int j = 0; j < 4; ++j) acc[i][j] = zf;

    constexpr int T = kD / 64;   // 16 K-tiles
    // prologue stage order: A0(0) A1(0) B0(0) B1(0) -> buf0; B0(1) B1(1) -> buf1
    stageA(0, 0); stageA(0, 1); stageB(0, 0); stageB(0, 1);
    stageB(1, 0); stageB(1, 1);

    bf16x8 af[8], bfl[4], bfh[4];

    for (int t = 0; t < T; ++t) {
        const int cb = t & 1, nb = cb ^ 1;
        const bool pf1 = (t + 1 < T);
        const bool pf2 = (t + 2 < T);
        const u16* cA = sA[cb];
        const u16* cB = sB[cb];

        // ========= ph0: stage A0(t+1); whole-tile guard; reads; MFMA Q00
        if (pf1) stageA(nb, 0);
        if (t < T - 1) asm volatile("s_waitcnt vmcnt(6)" ::: "memory");
        else           asm volatile("s_waitcnt vmcnt(0)" ::: "memory");
        __builtin_amdgcn_s_barrier();
        asm volatile("" ::: "memory");
#pragma unroll
        for (int i = 0; i < 4; ++i) {
            af[2 * i]     = *reinterpret_cast<const bf16x8*>(&cA[(wm + i * 16 + fm) * 64 + pc0]);
            af[2 * i + 1] = *reinterpret_cast<const bf16x8*>(&cA[(wm + i * 16 + fm) * 64 + pc1]);
        }
#pragma unroll
        for (int j = 0; j < 2; ++j) {
            bfl[2 * j]     = *reinterpret_cast<const bf16x8*>(&cB[(wn + j * 16 + fm) * 64 + pc0]);
            bfl[2 * j + 1] = *reinterpret_cast<const bf16x8*>(&cB[(wn + j * 16 + fm) * 64 + pc1]);
        }
        __builtin_amdgcn_s_setprio(1);
#pragma unroll
        for (int i = 0; i < 4; ++i)
#pragma unroll
            for (int j = 0; j < 2; ++j) {
                acc[i][j] = __builtin_amdgcn_mfma_f32_16x16x32_bf16(bfl[2 * j], af[2 * i], acc[i][j], 0, 0, 0);
                acc[i][j] = __builtin_amdgcn_mfma_f32_16x16x32_bf16(bfl[2 * j + 1], af[2 * i + 1], acc[i][j], 0, 0, 0);
            }
        __builtin_amdgcn_s_setprio(0);

        // ========= ph1: reads B1-range (pre-barrier); stage A1(t+1); MFMA Q01
#pragma unroll
        for (int j = 0; j < 2; ++j) {
            bfh[2 * j]     = *reinterpret_cast<const bf16x8*>(&cB[(wn + 32 + j * 16 + fm) * 64 + pc0]);
            bfh[2 * j + 1] = *reinterpret_cast<const bf16x8*>(&cB[(wn + 32 + j * 16 + fm) * 64 + pc1]);
        }
        if (pf1) stageA(nb, 1);
        asm volatile("" ::: "memory");
        __builtin_amdgcn_s_barrier();
        asm volatile("" ::: "memory");
        __builtin_amdgcn_s_setprio(1);
#pragma unroll
        for (int i = 0; i < 4; ++i)
#pragma unroll
            for (int j = 0; j < 2; ++j) {
                acc[i][2 + j] = __builtin_amdgcn_mfma_f32_16x16x32_bf16(bfh[2 * j], af[2 * i], acc[i][2 + j], 0, 0, 0);
                acc[i][2 + j] = __builtin_amdgcn_mfma_f32_16x16x32_bf16(bfh[2 * j + 1], af[2 * i + 1], acc[i][2 + j], 0, 0, 0);
            }
        __builtin_amdgcn_s_setprio(0);

        // ========= ph2: reads A hi-rows (pre-barrier); MFMA Q11
#pragma unroll
        for (int i = 0; i < 4; ++i) {
            af[2 * i]     = *reinterpret_cast<const bf16x8*>(&cA[(wm + 64 + i * 16 + fm) * 64 + pc0]);
            af[2 * i + 1] = *reinterpret_cast<const bf16x8*>(&cA[(wm + 64 + i * 16 + fm) * 64 + pc1]);
        }
        asm volatile("" ::: "memory");
        __builtin_amdgcn_s_barrier();
        asm volatile("" ::: "memory");
        __builtin_amdgcn_s_setprio(1);
#pragma unroll
        for (int i = 0; i < 4; ++i)
#pragma unroll
            for (int j = 0; j < 2; ++j) {
                acc[4 + i][2 + j] = __builtin_amdgcn_mfma_f32_16x16x32_bf16(bfh[2 * j], af[2 * i], acc[4 + i][2 + j], 0, 0, 0);
                acc[4 + i][2 + j] = __builtin_amdgcn_mfma_f32_16x16x32_bf16(bfh[2 * j + 1], af[2 * i + 1], acc[4 + i][2 + j], 0, 0, 0);
            }
        __builtin_amdgcn_s_setprio(0);

        // ========= ph3: stage B0(t+2)+B1(t+2); MFMA Q10 (register reuse)
        if (pf2) { stageB(cb, 0); stageB(cb, 1); }
        asm volatile("" ::: "memory");
        __builtin_amdgcn_s_barrier();
        asm volatile("" ::: "memory");
        __builtin_amdgcn_s_setprio(1);
#pragma unroll
        for (int i = 0; i < 4; ++i)
#pragma unroll
            for (int j = 0; j < 2; ++j) {
                acc[4 + i][j] = __builtin_amdgcn_mfma_f32_16x16x32_bf16(bfl[2 * j], af[2 * i], acc[4 + i][j], 0, 0, 0);
                acc[4 + i][j] = __builtin_amdgcn_mfma_f32_16x16x32_bf16(bfl[2 * j + 1], af[2 * i + 1], acc[4 + i][j], 0, 0, 0);
            }
        __builtin_amdgcn_s_setprio(0);
    }

    // Transposed C/D: row = wm + i*16 + fm, col = wn + j*16 + g4*4 + reg
    const int cq = g4 * 4;
#pragma unroll
    for (int i = 0; i < 8; ++i) {
        int row = row0 + wm + i * 16 + fm;   // y_c fully padded: no guard
#pragma unroll
        for (int j = 0; j < 4; ++j) {
            int col = col0 + wn + j * 16 + cq;
            f32x4 v = acc[i][j];
            ushort4 o;
            o.x = f2bf(v[0]); o.y = f2bf(v[1]); o.z = f2bf(v[2]); o.w = f2bf(v[3]);
            *reinterpret_cast<ushort4*>(yc + (size_t)row * kD + col) = o;
        }
    }
}

// GEMM2: FROZEN at r14 structure (128x128, BK=32, 4 waves, 3-stage
// counted-vmcnt, 48KB LDS -> 3 blocks/CU). r15's deep-pipeline port
// regressed +38us (traded occupancy TLP for pipeline depth).
__global__ __launch_bounds__(256, 3) void gemm_mfma_gate(
    const u16* __restrict__ A, int lda,
    const u16* __restrict__ Bt, int ldb, int K,
    int M, const float* __restrict__ bias,
    float* __restrict__ Cf, const u16* __restrict__ uga, const float* __restrict__ xo)
{
    __shared__ u16 sA[3][128 * 32];
    __shared__ u16 sB[3][128 * 32];

    const int tid = threadIdx.x;
    const int wave = tid >> 6;
    const int lane = tid & 63;

    constexpr int GX = kD / 128;      // 8 col tiles
    constexpr int GY = kNpad / 128;   // 80 row tiles
    const int lin = blockIdx.y * GX + blockIdx.x;
    const int xcd = lin & 7;          // default XCD of this block
    const int pos = lin >> 3;         // 0..79 within this XCD
    const int ty = xcd * (GY / 8) + (pos >> 3);
    const int tx = pos & 7;

    const int row0 = ty * 128;
    const int col0 = tx * 128;

    const int srow = wave * 16 + (lane >> 2);
    const int scol = (((lane & 3) ^ ((srow >> 1) & 3)) * 8);     // swizzled source chunk

    const u16* gA0 = A + (size_t)(row0 + srow) * lda + scol;
    const u16* gA1 = A + (size_t)(row0 + 64 + srow) * lda + scol;
    const u16* gB0 = Bt + (size_t)(col0 + srow) * ldb + scol;
    const u16* gB1 = Bt + (size_t)(col0 + 64 + srow) * ldb + scol;

    const int lof0 = (wave * 16) * 32;
    const int lof1 = (64 + wave * 16) * 32;

    const int mq = (wave >> 1) * 64;
    const int nq = (wave & 1) * 64;
    const int fm = lane & 15;
    const int fkx = (((lane >> 4) ^ ((fm >> 1) & 3))) * 8;       // swizzled read chunk

    f32x4 zf = {0.0f, 0.0f, 0.0f, 0.0f};
    f32x4 acc[4][4];
#pragma unroll
    for (int i = 0; i < 4; ++i)
#pragma unroll
        for (int j = 0; j < 4; ++j) acc[i][j] = zf;

    auto stage = [&](int s) {
        __builtin_amdgcn_global_load_lds(GLB(gA0), LDSP(sA[s] + lof0), 16, 0, 0);
        __builtin_amdgcn_global_load_lds(GLB(gA1), LDSP(sA[s] + lof1), 16, 0, 0);
        __builtin_amdgcn_global_load_lds(GLB(gB0), LDSP(sB[s] + lof0), 16, 0, 0);
        __builtin_amdgcn_global_load_lds(GLB(gB1), LDSP(sB[s] + lof1), 16, 0, 0);
        gA0 += 32; gA1 += 32; gB0 += 32; gB1 += 32;
    };

    const int T = K >> 5;   // 64 K-steps
    stage(0);
    stage(1);

    int s = 0;
    for (int t = 0; t < T; ++t) {
        if (t + 2 < T) {
            stage(s == 0 ? 2 : (s - 1));          // (t+2)%3
            asm volatile("s_waitcnt vmcnt(8)" ::: "memory");
        } else if (t + 1 < T) {
            asm volatile("s_waitcnt vmcnt(4)" ::: "memory");
        } else {
            asm volatile("s_waitcnt vmcnt(0)" ::: "memory");
        }
        __builtin_amdgcn_s_barrier();
        asm volatile("" ::: "memory");

        const u16* cA = sA[s];
        const u16* cB = sB[s];
        bf16x8 af[4], bfr[4];
#pragma unroll
        for (int i = 0; i < 4; ++i)
            af[i] = *reinterpret_cast<const bf16x8*>(&cA[(mq + i * 16 + fm) * 32 + fkx]);
#pragma unroll
        for (int j = 0; j < 4; ++j)
            bfr[j] = *reinterpret_cast<const bf16x8*>(&cB[(nq + j * 16 + fm) * 32 + fkx]);
#pragma unroll
        for (int i = 0; i < 4; ++i)
#pragma unroll
            for (int j = 0; j < 4; ++j)
                acc[i][j] = __builtin_amdgcn_mfma_f32_16x16x32_bf16(bfr[j], af[i], acc[i][j], 0, 0, 0);

        asm volatile("" ::: "memory");
        __builtin_amdgcn_s_barrier();
        s = (s == 2) ? 0 : (s + 1);
    }

    const int cq = (lane >> 4) * 4;
#pragma unroll
    for (int i = 0; i < 4; ++i) {
        int row = row0 + mq + i * 16 + fm;
        if (row >= M) continue;
#pragma unroll
        for (int j = 0; j < 4; ++j) {
            int col = col0 + nq + j * 16 + cq;
            f32x4 v = acc[i][j];
            float4 bv = *reinterpret_cast<const float4*>(bias + col);
            v[0] += bv.x; v[1] += bv.y; v[2] += bv.z; v[3] += bv.w;
            ushort4 ur = *reinterpret_cast<const ushort4*>(uga + (size_t)row * kKz + col);
            float4 xr = *reinterpret_cast<const float4*>(xo + (size_t)row * kD + col);
            float4 h;
            h.x = tanhf(bf2f(ur.x)) * v[0] + xr.x * (1.0f - v[0]);
            h.y = tanhf(bf2f(ur.y)) * v[1] + xr.y * (1.0f - v[1]);
            h.z = tanhf(bf2f(ur.z)) * v[2] + xr.z * (1.0f - v[2]);
            h.w = tanhf(bf2f(ur.w)) * v[3] + xr.w * (1.0f - v[3]);
            *reinterpret_cast<float4*>(Cf + (size_t)row * kD + col) = h;
        }
    }
}

extern "C" void kernel_launch(void* const* d_in, const int* in_sizes, int n_in,
                              void* d_out, int out_size, void* d_ws, size_t ws_size,
                              hipStream_t stream) {
    (void)in_sizes; (void)n_in; (void)out_size; (void)ws_size;

    const float* x     = (const float*)d_in[0];
    const int* eidx    = (const int*)d_in[1];
    const int* etype   = (const int*)d_in[2];
    const float* weight= (const float*)d_in[3];
    const float* root  = (const float*)d_in[4];
    const float* bias  = (const float*)d_in[5];
    const float* wgate = (const float*)d_in[6];
    const float* bgate = (const float*)d_in[7];
    float* out = (float*)d_out;

    const int* src = eidx;
    const int* dst = eidx + kE;

    // ---- workspace ----
    char* ws = (char*)d_ws;
    size_t off = 0;
    u16* yc   = (u16*)(ws + off);    off += (size_t)kCrows * kD * 2;   // 188.7 MB
    u16* ga   = (u16*)(ws + off);    off += (size_t)kNpad * kKz * 2;   //  41.9 MB
    u16* Bt9  = (u16*)(ws + off);    off += (size_t)(kR + 1) * kD * kD * 2; // 18.9 MB
    u16* wg_t = (u16*)(ws + off);    off += (size_t)kD * kKz * 2;      //   4.2 MB
    int* cntd    = (int*)(ws + off); off += (size_t)kN * 4;            // 10000
    int* flag    = (int*)(ws + off); off += (size_t)kR * kN * 4;       // 80000
    int* row_src = (int*)(ws + off); off += (size_t)kCrows * 4;        // 92160
    int* pos_tab = (int*)(ws + off); off += (size_t)kR * kN * 4;
    int* rowp    = (int*)(ws + off); off += (size_t)(kN + 16) * 4;
    int* curs    = (int*)(ws + off); off += (size_t)kN * 4;
    int* erec    = (int*)(ws + off); off += (size_t)kE * 4;
    int* relcnt9 = (int*)(ws + off); off += 16 * 4;

    // zero cntd+flag+row_src in one pass (contiguous, 182160 ints)
    zero16<<<180, 256, 0, stream>>>((uint4*)cntd, (long)(kN + kR * kN + kCrows) / 4);

    mark_edges<<<(kE + 255) / 256, 256, 0, stream>>>(src, dst, etype, cntd, flag);

    // fused: block 0 = rowptr scan, blocks 1..9 = per-relation compaction
    scan_combo<<<kR + 2, 1024, 0, stream>>>(cntd, rowp, curs, flag, row_src,
                                            pos_tab, relcnt9);

    fill_edges<<<(kE + 255) / 256, 256, 0, stream>>>(src, dst, etype, rowp, curs,
                                                     pos_tab, erec);

    // fused: x -> bf16 into ga[:,1024:2048] + zero pad rows [kN,kNpad)
    prep_ga<<<kNpad, 256, 0, stream>>>(x, ga);

    // fused: root/weight -> Bt9, wgate -> wg_t, one launch (z=0..10)
    {
        dim3 b(32, 8);
        transpose_all<<<dim3(kD / 32, kD / 32, 11), b, 0, stream>>>(root, weight,
                                                                    wgate, Bt9, wg_t);
    }

    // GEMM1 (compacted): y_c = gathered x rows @ per-relation W
    dim3 g1(kD / 256, kCrows / 256);   // 4 x 360, ~2/3 exit early
    gemm_compact<<<g1, 512, 0, stream>>>(ga + kD, kKz, Bt9, row_src, relcnt9, yc);

    // aggregate: u -> ga[:,0:1024] (bf16), 2 rows per block
    aggregate<<<kN / 2, 256, 0, stream>>>(yc, bias, rowp, erec, ga);

    // GEMM2: z = ga @ wg_t + b_gate; h = tanh(u)*z + x*(1-z) -> out
    dim3 g2(kD / 128, kNpad / 128);    // 8 x 80
    gemm_mfma_gate<<<g2, 256, 0, stream>>>(ga, kKz, wg_t, kKz, kKz, kN, bgate, out, ga, x);
}